// Round 10
// baseline (13.011 us; speedup 1.0000x reference)
//
#include <hip/hip_runtime.h>
#include <math.h>

#define NSEG   262144   // fullpath has 262145 points -> 262144 segments
#define NVERT  17
#define NBLK   1024     // NSEG / 256, one thread per segment

struct alignas(16) Partial { float w, f, l, pad; };

// ---------------- compile-time geometry (folds to inline literals) ----------
struct EdgeC { float qx, qy, sx, sy, dx, dy, c0, k; };

constexpr double csqrt_(double x) {
  double g = x > 1.0 ? x : 1.0;
  for (int i = 0; i < 64; ++i) g = 0.5 * (g + x / g);
  return g;
}
constexpr EdgeC mkedge(double qx, double qy, double nx, double ny) {
  double sx = nx - qx, sy = ny - qy;
  double n = csqrt_(sx * sx + sy * sy);
  double dx = sy / n, dy = -sx / n;
  return EdgeC{(float)qx, (float)qy, (float)sx, (float)sy,
               (float)dx, (float)dy, (float)(0.1 - (qx * dx + qy * dy)),
               (float)(qx * sy - qy * sx)};
}
constexpr EdgeC E[NVERT] = {
  // obstacle 0 (5)
  mkedge(1.23,3.47, 1.75,4.0), mkedge(1.75,4.0, 2.1,3.63), mkedge(2.1,3.63, 1.58,2.3),
  mkedge(1.58,2.3, 1.4,2.67),  mkedge(1.4,2.67, 1.23,3.47),
  // obstacle 1 (5)
  mkedge(4.65,5.98, 4.0,6.48), mkedge(4.0,6.48, 4.52,7.68), mkedge(4.52,7.68, 5.06,7.73),
  mkedge(5.06,7.73, 5.9,6.95), mkedge(5.9,6.95, 4.65,5.98),
  // obstacle 2 (3)
  mkedge(6.78,3.4, 7.78,5.1),  mkedge(7.78,5.1, 7.78,3.76), mkedge(7.78,3.76, 6.78,3.4),
  // obstacle 3 (4)
  mkedge(4.0,3.0, 4.35,3.35),  mkedge(4.35,3.35, 4.8,3.45), mkedge(4.8,3.45, 4.37,2.75),
  mkedge(4.37,2.75, 4.0,3.0)
};

__device__ __forceinline__ int imax_(int a, int b) { return a > b ? a : b; }
__device__ __forceinline__ int imin_(int a, int b) { return a < b ? a : b; }

// Sum over samples k=1..30 of prod_{e in [B0,B0+N)} relu(A[e] + (k/30)*B[e]).
// Product is nonzero exactly on f in (lo,hi) (intersection of half-lines);
// there it equals the degree-N polynomial prod(A + f*B).  Expand around the
// MIDPOINT of the included sample range: g = f - f0 with f0 = (k1+k2)/60.
// Included g-values are symmetric, so odd power-sums vanish and
//   S0 = n,  S2 = n(n^2-1)/12/900,  S4 = n(n^2-1)(3n^2-7)/240/810000.
// Midpoint-shifted factors are O(obstacle diameter), so coefficients are
// O(250) and f32 is numerically safe (tolerance is 2.7e4).
template<int B0, int N>
__device__ __forceinline__ float obstacle_sum(const float (&A)[NVERT],
                                              const float (&Bv)[NVERT]) {
  float lo = -1e30f, hi = 1e30f;
  #pragma unroll
  for (int e = B0; e < B0 + N; ++e) {
    const float b = Bv[e];
    float inv = __builtin_amdgcn_rcpf(b);
    inv = inv * (2.0f - b * inv);               // Newton refine
    const float fstar = -A[e] * inv;            // root of A + f*B
    const bool bp = b > 0.f;
    lo = fmaxf(lo, bp ? fstar : -1e30f);        // fmax/fmin drop NaN (b==0)
    hi = fminf(hi, bp ? 1e30f : fstar);
  }
  int k1 = (int)ceilf(lo * 30.f);               // cvt saturates on +-inf
  int k2 = (int)floorf(hi * 30.f);
  k1 = imin_(imax_(k1, 1), 31);
  k2 = imin_(imax_(k2, k1 - 1), 30);            // empty interval -> n == 0

  const float fn = (float)(k2 - k1 + 1);        // n in [0,30]
  const float f0 = (float)(k1 + k2) * (1.0f / 60.0f);
  const float n2 = fn * fn;
  const float S0 = fn;
  const float S2 = fn * (n2 - 1.f) * (1.f / (12.f * 900.f));
  const float S4 = fn * (n2 - 1.f) * fmaf(3.f, n2, -7.f) * (1.f / (240.f * 810000.f));

  // g-basis coefficients of prod (A'_e + g*B_e), A' = A + f0*B (all f32)
  float c[N + 1];
  c[0] = fmaf(f0, Bv[B0], A[B0]);
  c[1] = Bv[B0];
  #pragma unroll
  for (int e = B0 + 1; e < B0 + N; ++e) {
    const float Ad = fmaf(f0, Bv[e], A[e]);
    const float Bd = Bv[e];
    const int sz = e - B0 + 1;                  // #coeffs before this factor
    float prev = c[0];
    c[0] = Ad * c[0];
    #pragma unroll
    for (int j = 1; j < sz; ++j) {
      const float t = c[j];
      c[j] = fmaf(Ad, c[j], Bd * prev);
      prev = t;
    }
    c[sz] = Bd * prev;
  }

  float s = fmaf(c[2], S2, c[0] * S0);          // odd terms vanish by symmetry
  if constexpr (N >= 4) s = fmaf(c[4], S4, s);
  return s;
}

__global__ __launch_bounds__(256)
void path_cost_kernel(const float2* __restrict__ path,
                      const float2* __restrict__ st,
                      const float2* __restrict__ en,
                      Partial* __restrict__ ws) {
  const int i = blockIdx.x * 256 + threadIdx.x; // segment id (grid covers exactly)

  const float2 a = (i == 0)        ? *st : path[i - 1];
  const float2 b = (i == NSEG - 1) ? *en : path[i];
  const float rx = b.x - a.x, ry = b.y - a.y;

  float lpv = sqrtf(fmaf(ry, ry, fmaf(rx, rx, 1e-6f)));

  // ---- wzy: 0<t<1 && 0<u<1  <=>  min(nt,nu)>min(0,den) && max(nt,nu)<max(0,den)
  const float c = fmaf(a.x, ry, -(a.y * rx));   // ax*ry - ay*rx, hoisted
  int hits = 0;
  #pragma unroll
  for (int e = 0; e < NVERT; ++e) {
    const float den = fmaf(rx, E[e].sy, fmaf(-ry, E[e].sx, 1e-8f));
    const float nt  = fmaf(-a.x, E[e].sy, fmaf(a.y, E[e].sx, E[e].k));
    const float nu  = fmaf(E[e].qx, ry, -fmaf(E[e].qy, rx, c));
    const float mn  = fminf(nt, nu);
    const float mx  = fmaxf(nt, nu);
    hits += (mn > fminf(0.f, den)) && (mx < fmaxf(0.f, den));
  }
  float wzy = (float)hits;

  // ---- fxy: per-edge value affine in f: val = A[e] + f*B[e] (c0 includes +0.1)
  float A[NVERT], B[NVERT];
  #pragma unroll
  for (int e = 0; e < NVERT; ++e) {
    A[e] = fmaf(a.x, E[e].dx, fmaf(a.y, E[e].dy, E[e].c0));
    B[e] = fmaf(rx, E[e].dx, ry * E[e].dy);
  }
  float fxy = (obstacle_sum<0, 5>(A, B) + obstacle_sum<5, 5>(A, B)) +
              (obstacle_sum<10, 3>(A, B) + obstacle_sum<13, 4>(A, B));

  // ---- block reduction: wave64 shuffle -> LDS -> one float4 store ----
  #pragma unroll
  for (int o = 32; o > 0; o >>= 1) {
    wzy += __shfl_down(wzy, o);
    fxy += __shfl_down(fxy, o);
    lpv += __shfl_down(lpv, o);
  }
  __shared__ float sm[3][4];  // 256 threads = 4 waves
  const int wid = threadIdx.x >> 6;
  if ((threadIdx.x & 63) == 0) { sm[0][wid] = wzy; sm[1][wid] = fxy; sm[2][wid] = lpv; }
  __syncthreads();
  if (threadIdx.x == 0) {
    Partial p;
    p.w = (sm[0][0] + sm[0][1]) + (sm[0][2] + sm[0][3]);
    p.f = (sm[1][0] + sm[1][1]) + (sm[1][2] + sm[1][3]);
    p.l = (sm[2][0] + sm[2][1]) + (sm[2][2] + sm[2][3]);
    p.pad = 0.f;
    ws[blockIdx.x] = p;   // single global_store_dwordx4
  }
}

__global__ __launch_bounds__(256)
void reduce_kernel(const Partial* __restrict__ ws, float* __restrict__ out) {
  const int t = threadIdx.x;  // 256 threads, one block
  float w = 0.f, f = 0.f, l = 0.f;
  #pragma unroll
  for (int j = 0; j < NBLK / 256; ++j) {
    const Partial p = ws[t + j * 256];   // coalesced dwordx4
    w += p.w; f += p.f; l += p.l;
  }
  #pragma unroll
  for (int o = 32; o > 0; o >>= 1) {
    w += __shfl_down(w, o);
    f += __shfl_down(f, o);
    l += __shfl_down(l, o);
  }
  __shared__ float sm[3][4];
  const int wid = t >> 6;
  if ((t & 63) == 0) { sm[0][wid] = w; sm[1][wid] = f; sm[2][wid] = l; }
  __syncthreads();
  if (t == 0) {
    out[0] = (sm[0][0] + sm[0][1]) + (sm[0][2] + sm[0][3]);
    out[1] = (sm[1][0] + sm[1][1]) + (sm[1][2] + sm[1][3]);
    out[2] = (sm[2][0] + sm[2][1]) + (sm[2][2] + sm[2][3]);
  }
}

extern "C" void kernel_launch(void* const* d_in, const int* in_sizes, int n_in,
                              void* d_out, int out_size, void* d_ws, size_t ws_size,
                              hipStream_t stream) {
  (void)in_sizes; (void)n_in; (void)out_size; (void)ws_size;

  const float2* path = (const float2*)d_in[0];  // (262143, 2) f32
  const float2* st   = (const float2*)d_in[1];  // (2,) f32
  const float2* en   = (const float2*)d_in[2];  // (2,) f32
  Partial* ws = (Partial*)d_ws;                 // NBLK * 16 bytes
  float* out = (float*)d_out;                   // 3 f32

  path_cost_kernel<<<NBLK, 256, 0, stream>>>(path, st, en, ws);
  reduce_kernel<<<1, 256, 0, stream>>>(ws, out);
}

// Round 11
// 12.401 us; speedup vs baseline: 1.0492x; 1.0492x over previous
//
#include <hip/hip_runtime.h>
#include <math.h>

#define NSEG   262144   // fullpath has 262145 points -> 262144 segments
#define NVERT  17
#define NBLK   1024     // NSEG / 256, one thread per segment

struct alignas(16) Partial { float w, f, l, pad; };

// ---------------- compile-time geometry (folds to inline literals) ----------
struct EdgeC { float qx, qy, sx, sy, dx, dy, c0, k; };

constexpr double csqrt_(double x) {
  double g = x > 1.0 ? x : 1.0;
  for (int i = 0; i < 64; ++i) g = 0.5 * (g + x / g);
  return g;
}
constexpr EdgeC mkedge(double qx, double qy, double nx, double ny) {
  double sx = nx - qx, sy = ny - qy;
  double n = csqrt_(sx * sx + sy * sy);
  double dx = sy / n, dy = -sx / n;
  return EdgeC{(float)qx, (float)qy, (float)sx, (float)sy,
               (float)dx, (float)dy, (float)(0.1 - (qx * dx + qy * dy)),
               (float)(qx * sy - qy * sx)};
}
constexpr EdgeC E[NVERT] = {
  // obstacle 0 (5)
  mkedge(1.23,3.47, 1.75,4.0), mkedge(1.75,4.0, 2.1,3.63), mkedge(2.1,3.63, 1.58,2.3),
  mkedge(1.58,2.3, 1.4,2.67),  mkedge(1.4,2.67, 1.23,3.47),
  // obstacle 1 (5)
  mkedge(4.65,5.98, 4.0,6.48), mkedge(4.0,6.48, 4.52,7.68), mkedge(4.52,7.68, 5.06,7.73),
  mkedge(5.06,7.73, 5.9,6.95), mkedge(5.9,6.95, 4.65,5.98),
  // obstacle 2 (3)
  mkedge(6.78,3.4, 7.78,5.1),  mkedge(7.78,5.1, 7.78,3.76), mkedge(7.78,3.76, 6.78,3.4),
  // obstacle 3 (4)
  mkedge(4.0,3.0, 4.35,3.35),  mkedge(4.35,3.35, 4.8,3.45), mkedge(4.8,3.45, 4.37,2.75),
  mkedge(4.37,2.75, 4.0,3.0)
};

// Power-sum table: TD.v[m][j] = sum_{k=1..m} (k/30)^j, m=0..30, j=0..5 (f64)
struct TdTab { double v[31][6]; };
constexpr TdTab mktab() {
  TdTab t{};
  for (int m = 0; m <= 30; ++m)
    for (int j = 0; j < 6; ++j) {
      double s = 0.0;
      for (int k = 1; k <= m; ++k) {
        double f = k / 30.0, p = 1.0;
        for (int q = 0; q < j; ++q) p *= f;
        s += p;
      }
      t.v[m][j] = s;
    }
  return t;
}
__device__ constexpr TdTab TD = mktab();

__device__ __forceinline__ int imax_(int a, int b) { return a > b ? a : b; }
__device__ __forceinline__ int imin_(int a, int b) { return a < b ? a : b; }

// Sum over samples k=1..30 of prod_{e in [B0,B0+N)} relu(A[e] + (k/30)*B[e]).
// Nonzero iff all factors > 0 <=> f in (lo,hi); there it equals the degree-N
// polynomial prod(A+fB), summed exactly via power-sum table differences.
template<int B0, int N>
__device__ __forceinline__ double obstacle_sum(const float (&A)[NVERT],
                                               const float (&Bv)[NVERT],
                                               const double (&Td)[31][6]) {
  float lo = -1e30f, hi = 1e30f;
  #pragma unroll
  for (int e = B0; e < B0 + N; ++e) {
    const float b = Bv[e];
    float inv = __builtin_amdgcn_rcpf(b);
    inv = inv * (2.0f - b * inv);               // Newton refine
    const float fstar = -A[e] * inv;            // root of A + f*B
    const bool bp = b > 0.f;
    lo = fmaxf(lo, bp ? fstar : -1e30f);
    hi = fminf(hi, bp ? 1e30f : fstar);
  }
  int k1 = (int)ceilf(lo * 30.f);               // cvt saturates on +-inf
  int k2 = (int)floorf(hi * 30.f);
  k1 = imin_(imax_(k1, 1), 31);
  k2 = imin_(imax_(k2, k1 - 1), 30);            // empty interval -> k2 == k1-1
  const int m1 = k1 - 1;                        // in [0,30]

  // coefficients of prod (A_e + f*B_e), f64 (monomial expansion cancels badly in f32)
  double c[N + 1];
  c[0] = (double)A[B0];
  c[1] = (double)Bv[B0];
  #pragma unroll
  for (int e = B0 + 1; e < B0 + N; ++e) {
    const double Ad = (double)A[e], Bd = (double)Bv[e];
    const int sz = e - B0 + 1;                  // #coeffs before this factor
    double prev = c[0];
    c[0] = Ad * c[0];
    #pragma unroll
    for (int j = 1; j < sz; ++j) {
      const double t = c[j];
      c[j] = fma(Ad, c[j], Bd * prev);
      prev = t;
    }
    c[sz] = Bd * prev;
  }

  double s = 0.0;
  #pragma unroll
  for (int j = 0; j <= N; ++j)
    s = fma(c[j], Td[k2][j] - Td[m1][j], s);
  return s;
}

__global__ __launch_bounds__(256)
void path_cost_kernel(const float2* __restrict__ path,
                      const float2* __restrict__ st,
                      const float2* __restrict__ en,
                      Partial* __restrict__ ws) {
  __shared__ double Td[31][6];
  if (threadIdx.x < 186)                        // stage constexpr table to LDS
    ((double*)Td)[threadIdx.x] = ((const double*)TD.v)[threadIdx.x];
  __syncthreads();

  const int i = blockIdx.x * 256 + threadIdx.x; // segment id (grid covers exactly)

  const float2 a = (i == 0)        ? *st : path[i - 1];
  const float2 b = (i == NSEG - 1) ? *en : path[i];
  const float rx = b.x - a.x, ry = b.y - a.y;

  float lpv = sqrtf(fmaf(ry, ry, fmaf(rx, rx, 1e-6f)));

  // ---- wzy: 0<t<1 && 0<u<1  <=>  min(nt,nu)>min(0,den) && max(nt,nu)<max(0,den)
  const float c = fmaf(a.x, ry, -(a.y * rx));   // ax*ry - ay*rx, hoisted
  int hits = 0;
  #pragma unroll
  for (int e = 0; e < NVERT; ++e) {
    const float den = fmaf(rx, E[e].sy, fmaf(-ry, E[e].sx, 1e-8f));
    const float nt  = fmaf(-a.x, E[e].sy, fmaf(a.y, E[e].sx, E[e].k));
    const float nu  = fmaf(E[e].qx, ry, -fmaf(E[e].qy, rx, c));
    const float mn  = fminf(nt, nu);
    const float mx  = fmaxf(nt, nu);
    hits += (mn > fminf(0.f, den)) && (mx < fmaxf(0.f, den));
  }
  float wzy = (float)hits;

  // ---- fxy: per-edge value affine in f: val = A[e] + f*B[e] (c0 includes +0.1)
  float A[NVERT], B[NVERT];
  #pragma unroll
  for (int e = 0; e < NVERT; ++e) {
    A[e] = fmaf(a.x, E[e].dx, fmaf(a.y, E[e].dy, E[e].c0));
    B[e] = fmaf(rx, E[e].dx, ry * E[e].dy);
  }
  const double s0 = obstacle_sum<0, 5>(A, B, Td);
  const double s1 = obstacle_sum<5, 5>(A, B, Td);
  const double s2 = obstacle_sum<10, 3>(A, B, Td);
  const double s3 = obstacle_sum<13, 4>(A, B, Td);
  float fxy = (float)((s0 + s1) + (s2 + s3));

  // ---- block reduction: wave64 shuffle -> LDS -> one float4 store ----
  #pragma unroll
  for (int o = 32; o > 0; o >>= 1) {
    wzy += __shfl_down(wzy, o);
    fxy += __shfl_down(fxy, o);
    lpv += __shfl_down(lpv, o);
  }
  __shared__ float sm[3][4];  // 256 threads = 4 waves
  const int wid = threadIdx.x >> 6;
  if ((threadIdx.x & 63) == 0) { sm[0][wid] = wzy; sm[1][wid] = fxy; sm[2][wid] = lpv; }
  __syncthreads();
  if (threadIdx.x == 0) {
    Partial p;
    p.w = (sm[0][0] + sm[0][1]) + (sm[0][2] + sm[0][3]);
    p.f = (sm[1][0] + sm[1][1]) + (sm[1][2] + sm[1][3]);
    p.l = (sm[2][0] + sm[2][1]) + (sm[2][2] + sm[2][3]);
    p.pad = 0.f;
    ws[blockIdx.x] = p;   // single global_store_dwordx4
  }
}

__global__ __launch_bounds__(256)
void reduce_kernel(const Partial* __restrict__ ws, float* __restrict__ out) {
  const int t = threadIdx.x;  // 256 threads, one block
  float w = 0.f, f = 0.f, l = 0.f;
  #pragma unroll
  for (int j = 0; j < NBLK / 256; ++j) {
    const Partial p = ws[t + j * 256];   // coalesced dwordx4
    w += p.w; f += p.f; l += p.l;
  }
  #pragma unroll
  for (int o = 32; o > 0; o >>= 1) {
    w += __shfl_down(w, o);
    f += __shfl_down(f, o);
    l += __shfl_down(l, o);
  }
  __shared__ float sm[3][4];
  const int wid = t >> 6;
  if ((t & 63) == 0) { sm[0][wid] = w; sm[1][wid] = f; sm[2][wid] = l; }
  __syncthreads();
  if (t == 0) {
    out[0] = (sm[0][0] + sm[0][1]) + (sm[0][2] + sm[0][3]);
    out[1] = (sm[1][0] + sm[1][1]) + (sm[1][2] + sm[1][3]);
    out[2] = (sm[2][0] + sm[2][1]) + (sm[2][2] + sm[2][3]);
  }
}

extern "C" void kernel_launch(void* const* d_in, const int* in_sizes, int n_in,
                              void* d_out, int out_size, void* d_ws, size_t ws_size,
                              hipStream_t stream) {
  (void)in_sizes; (void)n_in; (void)out_size; (void)ws_size;

  const float2* path = (const float2*)d_in[0];  // (262143, 2) f32
  const float2* st   = (const float2*)d_in[1];  // (2,) f32
  const float2* en   = (const float2*)d_in[2];  // (2,) f32
  Partial* ws = (Partial*)d_ws;                 // NBLK * 16 bytes
  float* out = (float*)d_out;                   // 3 f32

  path_cost_kernel<<<NBLK, 256, 0, stream>>>(path, st, en, ws);
  reduce_kernel<<<1, 256, 0, stream>>>(ws, out);
}